// Round 3
// baseline (404.169 us; speedup 1.0000x reference)
//
#include <hip/hip_runtime.h>
#include <stdint.h>

#define IN_F   2048
#define OUT_F  2048
#define NROWS  8192   // 4 * 2048
#define BK     64
#define BM     256    // block M tile
#define BN     128    // block N tile
#define NTILES (IN_F / BK)   // 32 K-tiles

typedef __bf16 bf16x8 __attribute__((ext_vector_type(8)));
typedef float  f32x16 __attribute__((ext_vector_type(16)));
typedef unsigned short ushort8v __attribute__((ext_vector_type(8)));

// ---------- helpers ----------

__device__ __forceinline__ unsigned short f2bf_rtne(float f) {
    unsigned int u = __float_as_uint(f);
    u += 0x7FFFu + ((u >> 16) & 1u);   // round-to-nearest-even on bf16 boundary
    return (unsigned short)(u >> 16);
}

__device__ __forceinline__ float softplusf(float v) {
    float a = fabsf(v);
    return fmaxf(v, 0.0f) + log1pf(__expf(-a));
}

// async global->LDS, 16B per lane; LDS dest is wave-uniform base + lane*16
__device__ __forceinline__ void gload_lds16(const void* g, void* l) {
    __builtin_amdgcn_global_load_lds(
        (const __attribute__((address_space(1))) unsigned int*)g,
        (__attribute__((address_space(3))) unsigned int*)l,
        16 /*bytes*/, 0 /*offset*/, 0 /*aux*/);
}

// ---------- prep: fused fp32 -> bf16 conversions into workspace ----------

__global__ __launch_bounds__(256)
void prep_kernel(const float* __restrict__ x, const float* __restrict__ mu,
                 const float* __restrict__ sg,
                 unsigned short* __restrict__ xb, unsigned short* __restrict__ kh,
                 unsigned short* __restrict__ mh) {
    const int b = blockIdx.x;
    const int t = threadIdx.x;
    if (b < 8192) {
        const size_t i = ((size_t)b * 256 + t) * 8;
        float4 v0 = *(const float4*)(x + i);
        float4 v1 = *(const float4*)(x + i + 4);
        ushort8v o;
        o[0] = f2bf_rtne(v0.x); o[1] = f2bf_rtne(v0.y);
        o[2] = f2bf_rtne(v0.z); o[3] = f2bf_rtne(v0.w);
        o[4] = f2bf_rtne(v1.x); o[5] = f2bf_rtne(v1.y);
        o[6] = f2bf_rtne(v1.z); o[7] = f2bf_rtne(v1.w);
        *(ushort8v*)(xb + i) = o;
    } else {
        const size_t i = ((size_t)(b - 8192) * 256 + t) * 8;
        float4 m0 = *(const float4*)(mu + i);
        float4 m1 = *(const float4*)(mu + i + 4);
        float4 s0 = *(const float4*)(sg + i);
        float4 s1 = *(const float4*)(sg + i + 4);
        ushort8v ko, mo;
        ko[0] = f2bf_rtne(m0.x * softplusf(s0.x));
        ko[1] = f2bf_rtne(m0.y * softplusf(s0.y));
        ko[2] = f2bf_rtne(m0.z * softplusf(s0.z));
        ko[3] = f2bf_rtne(m0.w * softplusf(s0.w));
        ko[4] = f2bf_rtne(m1.x * softplusf(s1.x));
        ko[5] = f2bf_rtne(m1.y * softplusf(s1.y));
        ko[6] = f2bf_rtne(m1.z * softplusf(s1.z));
        ko[7] = f2bf_rtne(m1.w * softplusf(s1.w));
        mo[0] = f2bf_rtne(m0.x); mo[1] = f2bf_rtne(m0.y);
        mo[2] = f2bf_rtne(m0.z); mo[3] = f2bf_rtne(m0.w);
        mo[4] = f2bf_rtne(m1.x); mo[5] = f2bf_rtne(m1.y);
        mo[6] = f2bf_rtne(m1.z); mo[7] = f2bf_rtne(m1.w);
        *(ushort8v*)(kh + i) = ko;
        *(ushort8v*)(mh + i) = mo;
    }
}

// ---------- fused double-GEMM, intra-tile software-pipelined ----------
// BM=256 x BN=128, BK=64, 8 waves, wave tile 64x64 dual-acc sharing A-frags.
// LDS layout (identical to verified r2): [AL|AH|BL|BH] x 2 buffers = 128 KB,
// chunk swizzle phys = c ^ ((row>>1)&3) on both DMA source and read side.
// Per K-tile (2 barriers, vmcnt never drained mid-loop):
//   f0,f1 reads issue; STAGE_LOW(t+1); MFMA(f0) overlaps f1's lgkm drain;
//   vmcnt(4) [high(t) landed] -> barrier -> f2 reads; STAGE_HIGH(t+1);
//   MFMA(f1) overlaps f2; f3 reads; MFMA(f2) overlaps f3; vmcnt(4)
//   [low(t+1) landed] -> MFMA(f3) -> barrier.
// Every cross-wave visibility point is counted-wait THEN barrier. The
// compiler's own counted lgkmcnt keeps next-phase ds_reads in flight
// through each MFMA cluster -> LDS pipe and MFMA pipe overlap.

__global__ __launch_bounds__(512, 2)
void gemm_fused_kernel(const unsigned short* __restrict__ xb,  // [8192][2048] bf16
                       const unsigned short* __restrict__ kh,  // [2048][2048] bf16 keys
                       const unsigned short* __restrict__ mh,  // [2048][2048] bf16 mu
                       const float* __restrict__ gate,         // [2048]
                       float* __restrict__ out0,               // masked  [8192][2048]
                       float* __restrict__ out1,               // scores  [8192][2048]
                       float* __restrict__ out2)               // masked  [8192][2048]
{
    // [AL(2x8192) | AH(2x8192) | BL(2x8192: K@0,M@4096) | BH(2x8192)] ushorts
    __shared__ __align__(16) unsigned short lds[65536];   // 128 KB

    const int tid  = threadIdx.x;
    const int lane = tid & 63;
    const int wv   = tid >> 6;

    // XCD-aware bijective swizzle: 512 wgs, 8 XCDs, 64 consecutive wgs/XCD.
    const int swz = (blockIdx.x & 7) * 64 + (blockIdx.x >> 3);
    const int bm  = swz >> 4;    // 0..31 over M panels
    const int bo  = swz & 15;    // 0..15 over N panels

    const int wm = (wv >> 1) * 64;   // wave M offset: 0,64,128,192
    const int wn = (wv & 1) * 64;    // wave N offset: 0,64

    const int fm = lane & 31;
    const int hi = lane >> 5;

    // gate loads first: oldest VMEM ops, retire under the prologue vmcnt(4)
    const float g0 = gate[bo * BN + wn + fm];
    const float g1 = gate[bo * BN + wn + 32 + fm];

    // ---- staging lane constants (region = 16 rows x 32 cols = 1KB) ----
    const int rr   = lane >> 2;
    const int scol = ((lane & 3) ^ ((lane >> 3) & 3)) * 8;
    const unsigned short* sA0 = xb + (size_t)(bm * BM + wv * 32 + rr) * IN_F + scol;
    const unsigned short* sA1 = sA0 + (size_t)16 * IN_F;
    const unsigned short* sK  = kh + (size_t)(bo * BN + wv * 16 + rr) * IN_F + scol;
    const unsigned short* sM  = mh + (size_t)(bo * BN + wv * 16 + rr) * IN_F + scol;

    // ---- fragment read constants ----
    const int swf   = (fm >> 1) & 3;
    const int aoff0 = (wm +      fm) * 32;
    const int aoff1 = (wm + 32 + fm) * 32;
    const int boff0 = (wn +      fm) * 32;
    const int boff1 = (wn + 32 + fm) * 32;
    const int eE    = ((0 + hi) ^ swf) * 8;   // kc even chunk
    const int eO    = ((2 + hi) ^ swf) * 8;   // kc odd chunk

    f32x16 accS[2][2], accC[2][2];
#pragma unroll
    for (int i = 0; i < 2; ++i)
#pragma unroll
        for (int j = 0; j < 2; ++j)
#pragma unroll
            for (int r = 0; r < 16; ++r) { accS[i][j][r] = 0.f; accC[i][j][r] = 0.f; }

    auto STAGE_LOW = [&](int tt) {   // 4 gloads: A-low x2, K-low, M-low
        const int b2 = tt & 1;
        const int kt = tt * BK;
        unsigned short* ALb = &lds[b2 * 8192];
        unsigned short* BLb = &lds[32768 + b2 * 8192];
        gload_lds16(sA0 + kt, ALb + wv * 1024);
        gload_lds16(sA1 + kt, ALb + wv * 1024 + 512);
        gload_lds16(sK + kt, BLb + wv * 512);
        gload_lds16(sM + kt, BLb + 4096 + wv * 512);
    };
    auto STAGE_HIGH = [&](int tt) {  // 4 gloads: A-high x2, K-high, M-high
        const int b2 = tt & 1;
        const int kt = tt * BK + 32;
        unsigned short* AHb = &lds[16384 + b2 * 8192];
        unsigned short* BHb = &lds[49152 + b2 * 8192];
        gload_lds16(sA0 + kt, AHb + wv * 1024);
        gload_lds16(sA1 + kt, AHb + wv * 1024 + 512);
        gload_lds16(sK + kt, BHb + wv * 512);
        gload_lds16(sM + kt, BHb + 4096 + wv * 512);
    };

#define LDF(Abase, Bbase, e, a0, a1, k0, k1, m0, m1)                 \
    a0 = *(const bf16x8*)&(Abase)[aoff0 + (e)];                      \
    a1 = *(const bf16x8*)&(Abase)[aoff1 + (e)];                      \
    k0 = *(const bf16x8*)&(Bbase)[boff0 + (e)];                      \
    k1 = *(const bf16x8*)&(Bbase)[boff1 + (e)];                      \
    m0 = *(const bf16x8*)&(Bbase)[4096 + boff0 + (e)];               \
    m1 = *(const bf16x8*)&(Bbase)[4096 + boff1 + (e)];

#define MM8(a0, a1, k0, k1, m0, m1)                                                          \
    __builtin_amdgcn_s_setprio(1);                                                           \
    accS[0][0] = __builtin_amdgcn_mfma_f32_32x32x16_bf16(a0, k0, accS[0][0], 0, 0, 0);       \
    accS[0][1] = __builtin_amdgcn_mfma_f32_32x32x16_bf16(a0, k1, accS[0][1], 0, 0, 0);       \
    accS[1][0] = __builtin_amdgcn_mfma_f32_32x32x16_bf16(a1, k0, accS[1][0], 0, 0, 0);       \
    accS[1][1] = __builtin_amdgcn_mfma_f32_32x32x16_bf16(a1, k1, accS[1][1], 0, 0, 0);       \
    accC[0][0] = __builtin_amdgcn_mfma_f32_32x32x16_bf16(a0, m0, accC[0][0], 0, 0, 0);       \
    accC[0][1] = __builtin_amdgcn_mfma_f32_32x32x16_bf16(a0, m1, accC[0][1], 0, 0, 0);       \
    accC[1][0] = __builtin_amdgcn_mfma_f32_32x32x16_bf16(a1, m0, accC[1][0], 0, 0, 0);       \
    accC[1][1] = __builtin_amdgcn_mfma_f32_32x32x16_bf16(a1, m1, accC[1][1], 0, 0, 0);       \
    __builtin_amdgcn_s_setprio(0);

#define VMW(n)  asm volatile("s_waitcnt vmcnt(" #n ")" ::: "memory")
#define BARX()  do { __builtin_amdgcn_s_barrier(); __builtin_amdgcn_sched_barrier(0); } while (0)

    // ---- prologue: stage tile 0; wait low half (counted), barrier ----
    STAGE_LOW(0);
    STAGE_HIGH(0);
    VMW(4);                 // gates + low(0) landed; high(0) 4 outstanding
    BARX();

    bf16x8 A0, A1, K0, K1, M0, M1;   // f0 (kc0)
    bf16x8 B0, B1, L0, L1, N0, N1;   // f1 (kc1)
    bf16x8 C0, C1, P0, P1, Q0, Q1;   // f2 (kc2)
    bf16x8 D0, D1, R0, R1, S0, S1;   // f3 (kc3)

    // ---- main loop: tiles 0..30, always staging t+1 ----
#pragma unroll 1
    for (int t = 0; t < NTILES - 1; ++t) {
        const int b = t & 1;
        const unsigned short* AL = &lds[b * 8192];
        const unsigned short* AH = &lds[16384 + b * 8192];
        const unsigned short* BL = &lds[32768 + b * 8192];
        const unsigned short* BH = &lds[49152 + b * 8192];

        LDF(AL, BL, eE, A0, A1, K0, K1, M0, M1);        // f0 reads
        STAGE_LOW(t + 1);                               // outst: high(t)4 + low(t+1)4
        LDF(AL, BL, eO, B0, B1, L0, L1, N0, N1);        // f1 reads (in flight under MM f0)
        MM8(A0, A1, K0, K1, M0, M1);                    // kc0
        VMW(4);                                         // high(t) landed (per-wave)
        BARX();                                         // -> high(t) landed globally
        LDF(AH, BH, eE, C0, C1, P0, P1, Q0, Q1);        // f2 reads
        STAGE_HIGH(t + 1);                              // outst: low(t+1)4 + high(t+1)4
        MM8(B0, B1, L0, L1, N0, N1);                    // kc1 (f2 drains under it)
        LDF(AH, BH, eO, D0, D1, R0, R1, S0, S1);        // f3 reads
        MM8(C0, C1, P0, P1, Q0, Q1);                    // kc2 (f3 drains under it)
        VMW(4);                                         // low(t+1) landed (per-wave)
        MM8(D0, D1, R0, R1, S0, S1);                    // kc3
        BARX();                                         // -> low(t+1) landed globally
    }

    // ---- tail tile 31: no staging; outstanding = high(31):4 ----
    {
        const int b = (NTILES - 1) & 1;
        const unsigned short* AL = &lds[b * 8192];
        const unsigned short* AH = &lds[16384 + b * 8192];
        const unsigned short* BL = &lds[32768 + b * 8192];
        const unsigned short* BH = &lds[49152 + b * 8192];

        LDF(AL, BL, eE, A0, A1, K0, K1, M0, M1);
        LDF(AL, BL, eO, B0, B1, L0, L1, N0, N1);
        MM8(A0, A1, K0, K1, M0, M1);
        VMW(0);                                         // high(31) landed
        BARX();
        LDF(AH, BH, eE, C0, C1, P0, P1, Q0, Q1);
        MM8(B0, B1, L0, L1, N0, N1);
        LDF(AH, BH, eO, D0, D1, R0, R1, S0, S1);
        MM8(C0, C1, P0, P1, Q0, Q1);
        MM8(D0, D1, R0, R1, S0, S1);
    }

    // ---- epilogue: 32x32 C/D layout: col=lane&31, row=(reg&3)+8*(reg>>2)+4*hi
    const float inv_sqrt_d = 0.022097086912079608f;  // 1/sqrt(2048)
    const size_t row_base = (size_t)bm * BM + wm;
    const int    col_base = bo * BN + wn;

#pragma unroll
    for (int i = 0; i < 2; ++i) {
#pragma unroll
        for (int j = 0; j < 2; ++j) {
            const float g   = j ? g1 : g0;
            const int   col = col_base + j * 32 + fm;
#pragma unroll
            for (int reg = 0; reg < 16; ++reg) {
                const int ro = (reg & 3) + 8 * (reg >> 2) + 4 * hi;
                const size_t row = row_base + i * 32 + ro;
                const size_t idx = row * OUT_F + col;
                const float s = accS[i][j][reg] * inv_sqrt_d;
                const float c = accC[i][j][reg];
                float w = s - g;
                w = w > 0.f ? w : 0.f;
                const float m = c * w;
                __builtin_nontemporal_store(m, &out0[idx]);
                __builtin_nontemporal_store(s, &out1[idx]);
                __builtin_nontemporal_store(m, &out2[idx]);
            }
        }
    }
#undef LDF
#undef MM8
#undef VMW
#undef BARX
}

// ---------- launch ----------

extern "C" void kernel_launch(void* const* d_in, const int* in_sizes, int n_in,
                              void* d_out, int out_size, void* d_ws, size_t ws_size,
                              hipStream_t stream) {
    const float* x    = (const float*)d_in[0];   // [4,2048,2048]
    const float* mu   = (const float*)d_in[1];   // [2048,2048]
    const float* sg   = (const float*)d_in[2];   // [2048,2048]
    const float* gate = (const float*)d_in[3];   // [2048]

    float* out0 = (float*)d_out;                         // final_output
    float* out1 = out0 + (size_t)NROWS * OUT_F;          // scores
    float* out2 = out1 + (size_t)NROWS * OUT_F;          // masked_output

    // workspace layout (bf16): xb 33.55MB | kh 8.39MB | mh 8.39MB  (50.3MB)
    unsigned short* xb = (unsigned short*)d_ws;
    unsigned short* kh = xb + (size_t)NROWS * IN_F;
    unsigned short* mh = kh + (size_t)OUT_F * IN_F;

    prep_kernel<<<8192 + 2048, 256, 0, stream>>>(x, mu, sg, xb, kh, mh);

    dim3 grid(NROWS / BM * (OUT_F / BN));  // 32 * 16 = 512 blocks
    gemm_fused_kernel<<<grid, 512, 0, stream>>>(xb, kh, mh, gate, out0, out1, out2);
}

// Round 4
// 400.202 us; speedup vs baseline: 1.0099x; 1.0099x over previous
//
#include <hip/hip_runtime.h>
#include <stdint.h>

#define IN_F   2048
#define OUT_F  2048
#define NROWS  8192   // 4 * 2048
#define BK     64
#define BM     256    // block M tile
#define BN     128    // block N tile
#define NTILES (IN_F / BK)   // 32 K-tiles

typedef __bf16 bf16x8 __attribute__((ext_vector_type(8)));
typedef float  f32x16 __attribute__((ext_vector_type(16)));
typedef unsigned short ushort8v __attribute__((ext_vector_type(8)));

// ---------- helpers ----------

__device__ __forceinline__ unsigned short f2bf_rtne(float f) {
    unsigned int u = __float_as_uint(f);
    u += 0x7FFFu + ((u >> 16) & 1u);   // round-to-nearest-even on bf16 boundary
    return (unsigned short)(u >> 16);
}

__device__ __forceinline__ float softplusf(float v) {
    float a = fabsf(v);
    return fmaxf(v, 0.0f) + log1pf(__expf(-a));
}

// async global->LDS, 16B per lane; LDS dest is wave-uniform base + lane*16
__device__ __forceinline__ void gload_lds16(const void* g, void* l) {
    __builtin_amdgcn_global_load_lds(
        (const __attribute__((address_space(1))) unsigned int*)g,
        (__attribute__((address_space(3))) unsigned int*)l,
        16 /*bytes*/, 0 /*offset*/, 0 /*aux*/);
}

// ---------- prep: fused fp32 -> bf16 conversions into workspace ----------

__global__ __launch_bounds__(256)
void prep_kernel(const float* __restrict__ x, const float* __restrict__ mu,
                 const float* __restrict__ sg,
                 unsigned short* __restrict__ xb, unsigned short* __restrict__ kh,
                 unsigned short* __restrict__ mh) {
    const int b = blockIdx.x;
    const int t = threadIdx.x;
    if (b < 8192) {
        const size_t i = ((size_t)b * 256 + t) * 8;
        float4 v0 = *(const float4*)(x + i);
        float4 v1 = *(const float4*)(x + i + 4);
        ushort8v o;
        o[0] = f2bf_rtne(v0.x); o[1] = f2bf_rtne(v0.y);
        o[2] = f2bf_rtne(v0.z); o[3] = f2bf_rtne(v0.w);
        o[4] = f2bf_rtne(v1.x); o[5] = f2bf_rtne(v1.y);
        o[6] = f2bf_rtne(v1.z); o[7] = f2bf_rtne(v1.w);
        *(ushort8v*)(xb + i) = o;
    } else {
        const size_t i = ((size_t)(b - 8192) * 256 + t) * 8;
        float4 m0 = *(const float4*)(mu + i);
        float4 m1 = *(const float4*)(mu + i + 4);
        float4 s0 = *(const float4*)(sg + i);
        float4 s1 = *(const float4*)(sg + i + 4);
        ushort8v ko, mo;
        ko[0] = f2bf_rtne(m0.x * softplusf(s0.x));
        ko[1] = f2bf_rtne(m0.y * softplusf(s0.y));
        ko[2] = f2bf_rtne(m0.z * softplusf(s0.z));
        ko[3] = f2bf_rtne(m0.w * softplusf(s0.w));
        ko[4] = f2bf_rtne(m1.x * softplusf(s1.x));
        ko[5] = f2bf_rtne(m1.y * softplusf(s1.y));
        ko[6] = f2bf_rtne(m1.z * softplusf(s1.z));
        ko[7] = f2bf_rtne(m1.w * softplusf(s1.w));
        mo[0] = f2bf_rtne(m0.x); mo[1] = f2bf_rtne(m0.y);
        mo[2] = f2bf_rtne(m0.z); mo[3] = f2bf_rtne(m0.w);
        mo[4] = f2bf_rtne(m1.x); mo[5] = f2bf_rtne(m1.y);
        mo[6] = f2bf_rtne(m1.z); mo[7] = f2bf_rtne(m1.w);
        *(ushort8v*)(kh + i) = ko;
        *(ushort8v*)(mh + i) = mo;
    }
}

// ---------- fused double-GEMM, 4-wave 128x64 tiles, pinned pipeline ----------
// BM=256 x BN=128, BK=64, 4 waves (2M x 2N), wave tile 128x64 dual-acc:
// per kc 8 ds_read_b128 (4 A + K0,K1 + M0,M1) feed 16 MFMAs = 64 FLOP/LDS-B
// (was 42.7). LDS read traffic per tile drops 192 -> 128 wave-b128, making
// LDS (~2560 cyc) ~ MFMA (2067 cyc) instead of 3584 vs 2067.
// 1 wave/SIMD (acc=256 regs needs the 512-VGPR budget); all latency hiding
// is ILP: frag reads of kc+1 are PINNED above the MFMA cluster of kc via
// sched_barrier(0) (r3 failure: compiler sank the reads, VGPR=108 proved
// the pipeline never materialized). Counted vmcnt(8), never 0 mid-loop.
// LDS layout identical to r2/r3: [AL|AH|BL|BH] x 2 = 128 KB, chunk swizzle
// phys = c ^ ((row>>1)&3) on both DMA source and read side.

__global__ __launch_bounds__(256, 1)
void gemm_fused_kernel(const unsigned short* __restrict__ xb,  // [8192][2048] bf16
                       const unsigned short* __restrict__ kh,  // [2048][2048] bf16 keys
                       const unsigned short* __restrict__ mh,  // [2048][2048] bf16 mu
                       const float* __restrict__ gate,         // [2048]
                       float* __restrict__ out0,               // masked  [8192][2048]
                       float* __restrict__ out1,               // scores  [8192][2048]
                       float* __restrict__ out2)               // masked  [8192][2048]
{
    // [AL(2x8192) | AH(2x8192) | BL(2x8192: K@0,M@4096) | BH(2x8192)] ushorts
    __shared__ __align__(16) unsigned short lds[65536];   // 128 KB

    const int tid  = threadIdx.x;
    const int lane = tid & 63;
    const int wv   = tid >> 6;       // 0..3

    // XCD-aware bijective swizzle: 512 wgs, 8 XCDs, 64 consecutive wgs/XCD.
    const int swz = (blockIdx.x & 7) * 64 + (blockIdx.x >> 3);
    const int bm  = swz >> 4;    // 0..31 over M panels
    const int bo  = swz & 15;    // 0..15 over N panels

    const int wm = (wv >> 1) * 128;  // wave M offset: 0,128
    const int wn = (wv & 1) * 64;    // wave N offset: 0,64

    const int fm = lane & 31;
    const int hi = lane >> 5;

    // gate loads: issued early or sunk by compiler; either way vmcnt math
    // stays valid (they never sit between in-loop staging ops)
    const float g0 = gate[bo * BN + wn + fm];
    const float g1 = gate[bo * BN + wn + 32 + fm];

    // ---- staging lane constants (region = 16 rows x 32 cols = 1KB) ----
    const int rr   = lane >> 2;
    const int scol = ((lane & 3) ^ ((lane >> 3) & 3)) * 8;
    const unsigned short* sA = xb + (size_t)(bm * BM + wv * 64 + rr) * IN_F + scol;
    const unsigned short* sK = kh + (size_t)(bo * BN + wv * 32 + rr) * IN_F + scol;
    const unsigned short* sM = mh + (size_t)(bo * BN + wv * 32 + rr) * IN_F + scol;

    // ---- fragment read constants ----
    const int swf = (fm >> 1) & 3;
    const int ao0 = (wm +      fm) * 32;
    const int ao1 = (wm +  32 + fm) * 32;
    const int ao2 = (wm +  64 + fm) * 32;
    const int ao3 = (wm +  96 + fm) * 32;
    const int no0 = (wn +      fm) * 32;
    const int no1 = (wn +  32 + fm) * 32;
    const int eE  = ((0 + hi) ^ swf) * 8;   // kc even chunk within a half
    const int eO  = ((2 + hi) ^ swf) * 8;   // kc odd chunk

    f32x16 accS[4][2], accC[4][2];
#pragma unroll
    for (int i = 0; i < 4; ++i)
#pragma unroll
        for (int j = 0; j < 2; ++j)
#pragma unroll
            for (int r = 0; r < 16; ++r) { accS[i][j][r] = 0.f; accC[i][j][r] = 0.f; }

    auto STAGE_LOW = [&](int tt) {   // 8 gloads: A x4, K x2, M x2
        const int b2 = tt & 1;
        const int kt = tt * BK;
        unsigned short* ALb = &lds[b2 * 8192];
        unsigned short* BLb = &lds[32768 + b2 * 8192];
        gload_lds16(sA + kt,                     ALb + (wv * 4 + 0) * 512);
        gload_lds16(sA + kt + (size_t)16 * IN_F, ALb + (wv * 4 + 1) * 512);
        gload_lds16(sA + kt + (size_t)32 * IN_F, ALb + (wv * 4 + 2) * 512);
        gload_lds16(sA + kt + (size_t)48 * IN_F, ALb + (wv * 4 + 3) * 512);
        gload_lds16(sK + kt,                     BLb + (wv * 2 + 0) * 512);
        gload_lds16(sK + kt + (size_t)16 * IN_F, BLb + (wv * 2 + 1) * 512);
        gload_lds16(sM + kt,                     BLb + 4096 + (wv * 2 + 0) * 512);
        gload_lds16(sM + kt + (size_t)16 * IN_F, BLb + 4096 + (wv * 2 + 1) * 512);
    };
    auto STAGE_HIGH = [&](int tt) {
        const int b2 = tt & 1;
        const int kt = tt * BK + 32;
        unsigned short* AHb = &lds[16384 + b2 * 8192];
        unsigned short* BHb = &lds[49152 + b2 * 8192];
        gload_lds16(sA + kt,                     AHb + (wv * 4 + 0) * 512);
        gload_lds16(sA + kt + (size_t)16 * IN_F, AHb + (wv * 4 + 1) * 512);
        gload_lds16(sA + kt + (size_t)32 * IN_F, AHb + (wv * 4 + 2) * 512);
        gload_lds16(sA + kt + (size_t)48 * IN_F, AHb + (wv * 4 + 3) * 512);
        gload_lds16(sK + kt,                     BHb + (wv * 2 + 0) * 512);
        gload_lds16(sK + kt + (size_t)16 * IN_F, BHb + (wv * 2 + 1) * 512);
        gload_lds16(sM + kt,                     BHb + 4096 + (wv * 2 + 0) * 512);
        gload_lds16(sM + kt + (size_t)16 * IN_F, BHb + 4096 + (wv * 2 + 1) * 512);
    };

#define LDFRAG(Ab, Bb, e, a0, a1, a2, a3, k0, k1, m0, m1)            \
    a0 = *(const bf16x8*)&(Ab)[ao0 + (e)];                           \
    a1 = *(const bf16x8*)&(Ab)[ao1 + (e)];                           \
    a2 = *(const bf16x8*)&(Ab)[ao2 + (e)];                           \
    a3 = *(const bf16x8*)&(Ab)[ao3 + (e)];                           \
    k0 = *(const bf16x8*)&(Bb)[no0 + (e)];                           \
    k1 = *(const bf16x8*)&(Bb)[no1 + (e)];                           \
    m0 = *(const bf16x8*)&(Bb)[4096 + no0 + (e)];                    \
    m1 = *(const bf16x8*)&(Bb)[4096 + no1 + (e)];

#define MM16(a0, a1, a2, a3, k0, k1, m0, m1)                                                 \
    __builtin_amdgcn_s_setprio(1);                                                           \
    accS[0][0] = __builtin_amdgcn_mfma_f32_32x32x16_bf16(a0, k0, accS[0][0], 0, 0, 0);       \
    accS[0][1] = __builtin_amdgcn_mfma_f32_32x32x16_bf16(a0, k1, accS[0][1], 0, 0, 0);       \
    accC[0][0] = __builtin_amdgcn_mfma_f32_32x32x16_bf16(a0, m0, accC[0][0], 0, 0, 0);       \
    accC[0][1] = __builtin_amdgcn_mfma_f32_32x32x16_bf16(a0, m1, accC[0][1], 0, 0, 0);       \
    accS[1][0] = __builtin_amdgcn_mfma_f32_32x32x16_bf16(a1, k0, accS[1][0], 0, 0, 0);       \
    accS[1][1] = __builtin_amdgcn_mfma_f32_32x32x16_bf16(a1, k1, accS[1][1], 0, 0, 0);       \
    accC[1][0] = __builtin_amdgcn_mfma_f32_32x32x16_bf16(a1, m0, accC[1][0], 0, 0, 0);       \
    accC[1][1] = __builtin_amdgcn_mfma_f32_32x32x16_bf16(a1, m1, accC[1][1], 0, 0, 0);       \
    accS[2][0] = __builtin_amdgcn_mfma_f32_32x32x16_bf16(a2, k0, accS[2][0], 0, 0, 0);       \
    accS[2][1] = __builtin_amdgcn_mfma_f32_32x32x16_bf16(a2, k1, accS[2][1], 0, 0, 0);       \
    accC[2][0] = __builtin_amdgcn_mfma_f32_32x32x16_bf16(a2, m0, accC[2][0], 0, 0, 0);       \
    accC[2][1] = __builtin_amdgcn_mfma_f32_32x32x16_bf16(a2, m1, accC[2][1], 0, 0, 0);       \
    accS[3][0] = __builtin_amdgcn_mfma_f32_32x32x16_bf16(a3, k0, accS[3][0], 0, 0, 0);       \
    accS[3][1] = __builtin_amdgcn_mfma_f32_32x32x16_bf16(a3, k1, accS[3][1], 0, 0, 0);       \
    accC[3][0] = __builtin_amdgcn_mfma_f32_32x32x16_bf16(a3, m0, accC[3][0], 0, 0, 0);       \
    accC[3][1] = __builtin_amdgcn_mfma_f32_32x32x16_bf16(a3, m1, accC[3][1], 0, 0, 0);       \
    __builtin_amdgcn_s_setprio(0);

#define SB0()   __builtin_amdgcn_sched_barrier(0)
#define VMW(n)  asm volatile("s_waitcnt vmcnt(" #n ")" ::: "memory")
#define BARX()  do { __builtin_amdgcn_s_barrier(); __builtin_amdgcn_sched_barrier(0); } while (0)

    // ---- prologue: stage tile 0; counted wait for low half; barrier ----
    STAGE_LOW(0);
    STAGE_HIGH(0);
    VMW(8);                 // low(0) (+gates if issued) landed; high(0) outstanding
    BARX();

    bf16x8 A0, A1, A2, A3, K0, K1, M0, M1;   // f0 (kc0)
    bf16x8 B0, B1, B2, B3, L0, L1, N0, N1;   // f1 (kc1)
    bf16x8 C0, C1, C2, C3, P0, P1, Q0, Q1;   // f2 (kc2)
    bf16x8 D0, D1, D2, D3, R0, R1, S0, S1;   // f3 (kc3)

    // ---- main loop: tiles 0..30, always staging t+1 ----
#pragma unroll 1
    for (int t = 0; t < NTILES - 1; ++t) {
        const int b = t & 1;
        const unsigned short* AL = &lds[b * 8192];
        const unsigned short* AH = &lds[16384 + b * 8192];
        const unsigned short* BL = &lds[32768 + b * 8192];
        const unsigned short* BH = &lds[49152 + b * 8192];

        LDFRAG(AL, BL, eE, A0, A1, A2, A3, K0, K1, M0, M1);   // f0 reads
        SB0();                                                 // pin above staging
        STAGE_LOW(t + 1);            // outst: high(t)8 + low(t+1)8
        LDFRAG(AL, BL, eO, B0, B1, B2, B3, L0, L1, N0, N1);   // f1 reads
        SB0();                                                 // pin f1 above MFMA f0
        MM16(A0, A1, A2, A3, K0, K1, M0, M1);                 // kc0 (f1 drains under it)
        VMW(8);                      // high(t) landed (per-wave)
        BARX();                      // -> high(t) landed globally
        LDFRAG(AH, BH, eE, C0, C1, C2, C3, P0, P1, Q0, Q1);   // f2 reads
        SB0();
        STAGE_HIGH(t + 1);           // outst: low(t+1)8 + high(t+1)8
        LDFRAG(AH, BH, eO, D0, D1, D2, D3, R0, R1, S0, S1);   // f3 reads
        SB0();                       // pin f2,f3 above MFMA f1
        MM16(B0, B1, B2, B3, L0, L1, N0, N1);                 // kc1 (f2 drains under it)
        MM16(C0, C1, C2, C3, P0, P1, Q0, Q1);                 // kc2 (f3 drains under it)
        VMW(8);                      // low(t+1) landed (per-wave)
        MM16(D0, D1, D2, D3, R0, R1, S0, S1);                 // kc3
        BARX();                      // -> low(t+1) landed globally
    }

    // ---- tail tile 31: no staging; outstanding = high(31):8 ----
    {
        const int b = (NTILES - 1) & 1;
        const unsigned short* AL = &lds[b * 8192];
        const unsigned short* AH = &lds[16384 + b * 8192];
        const unsigned short* BL = &lds[32768 + b * 8192];
        const unsigned short* BH = &lds[49152 + b * 8192];

        LDFRAG(AL, BL, eE, A0, A1, A2, A3, K0, K1, M0, M1);
        SB0();
        LDFRAG(AL, BL, eO, B0, B1, B2, B3, L0, L1, N0, N1);
        SB0();
        MM16(A0, A1, A2, A3, K0, K1, M0, M1);
        VMW(0);                      // high(31) landed
        BARX();
        LDFRAG(AH, BH, eE, C0, C1, C2, C3, P0, P1, Q0, Q1);
        SB0();
        LDFRAG(AH, BH, eO, D0, D1, D2, D3, R0, R1, S0, S1);
        SB0();
        MM16(B0, B1, B2, B3, L0, L1, N0, N1);
        MM16(C0, C1, C2, C3, P0, P1, Q0, Q1);
        MM16(D0, D1, D2, D3, R0, R1, S0, S1);
    }

    // ---- epilogue: 32x32 C/D layout: col=lane&31, row=(reg&3)+8*(reg>>2)+4*hi
    const float inv_sqrt_d = 0.022097086912079608f;  // 1/sqrt(2048)
    const size_t row_base = (size_t)bm * BM + wm;
    const int    col_base = bo * BN + wn;

#pragma unroll
    for (int i = 0; i < 4; ++i) {
#pragma unroll
        for (int j = 0; j < 2; ++j) {
            const float g   = j ? g1 : g0;
            const int   col = col_base + j * 32 + fm;
#pragma unroll
            for (int reg = 0; reg < 16; ++reg) {
                const int ro = (reg & 3) + 8 * (reg >> 2) + 4 * hi;
                const size_t row = row_base + i * 32 + ro;
                const size_t idx = row * OUT_F + col;
                const float s = accS[i][j][reg] * inv_sqrt_d;
                const float c = accC[i][j][reg];
                float w = s - g;
                w = w > 0.f ? w : 0.f;
                const float m = c * w;
                __builtin_nontemporal_store(m, &out0[idx]);
                __builtin_nontemporal_store(s, &out1[idx]);
                __builtin_nontemporal_store(m, &out2[idx]);
            }
        }
    }
#undef LDFRAG
#undef MM16
#undef SB0
#undef VMW
#undef BARX
}

// ---------- launch ----------

extern "C" void kernel_launch(void* const* d_in, const int* in_sizes, int n_in,
                              void* d_out, int out_size, void* d_ws, size_t ws_size,
                              hipStream_t stream) {
    const float* x    = (const float*)d_in[0];   // [4,2048,2048]
    const float* mu   = (const float*)d_in[1];   // [2048,2048]
    const float* sg   = (const float*)d_in[2];   // [2048,2048]
    const float* gate = (const float*)d_in[3];   // [2048]

    float* out0 = (float*)d_out;                         // final_output
    float* out1 = out0 + (size_t)NROWS * OUT_F;          // scores
    float* out2 = out1 + (size_t)NROWS * OUT_F;          // masked_output

    // workspace layout (bf16): xb 33.55MB | kh 8.39MB | mh 8.39MB  (50.3MB)
    unsigned short* xb = (unsigned short*)d_ws;
    unsigned short* kh = xb + (size_t)NROWS * IN_F;
    unsigned short* mh = kh + (size_t)OUT_F * IN_F;

    prep_kernel<<<8192 + 2048, 256, 0, stream>>>(x, mu, sg, xb, kh, mh);

    dim3 grid(NROWS / BM * (OUT_F / BN));  // 32 * 16 = 512 blocks
    gemm_fused_kernel<<<grid, 256, 0, stream>>>(xb, kh, mh, gate, out0, out1, out2);
}